// Round 7
// baseline (139.219 us; speedup 1.0000x reference)
//
#include <hip/hip_runtime.h>
#include <hip/hip_bf16.h>

// y[n,g,h] = sum_k x[n,g,k] * H[g,k,h]
// x: [ntok, 4096] fp32, H: [64, 64, 64] fp32, y: [ntok, 4096] fp32.
// Memory-bound. R7 = R6 (LDS-transpose -> 256B-contiguous NT stores) +
// explicit barriers around the LDS handoff. R6 failed correctness: the
// cross-lane ds_write -> ds_read handoff had no fence; the compiler's
// single-thread model can't see the dependency. __syncthreads() (waitcnt
// lgkmcnt(0) + s_barrier) makes the ordering architectural.

#define DIM 4096
#define NG   64   // groups per token
#define GSZ  64   // group size
#define TOK_PER_BLK 512
#define TILES 8   // 16-token tiles per wave
#define LDT  68   // transpose stride in floats: 272B = 16B-aligned, odd 16B-groups

typedef __bf16 bf16x8 __attribute__((ext_vector_type(8)));
typedef float  f32x4  __attribute__((ext_vector_type(4)));

__global__ __launch_bounds__(256, 8)
void hh_mfma_kernel(const float* __restrict__ x, const float* __restrict__ H,
                    float* __restrict__ y, int ntok) {
    __shared__ __align__(16) float Tl[4][16][LDT];   // 17408 B, per-wave regions

    const int g    = blockIdx.x & (NG - 1);
    const int tb   = blockIdx.x >> 6;
    const int lane = threadIdx.x & 63;
    const int wave = threadIdx.x >> 6;

    // ---- build H^T fragments (A operand) straight from global (L2-hot) ----
    const int hcol = lane & 15;
    const int hrow = (lane >> 4) * 8;
    const float* __restrict__ Hg = H + (size_t)g * (GSZ * GSZ);
    bf16x8 hfrag[2][4];
    #pragma unroll
    for (int kt = 0; kt < 2; ++kt)
        #pragma unroll
        for (int ht = 0; ht < 4; ++ht)
            #pragma unroll
            for (int i = 0; i < 8; ++i)
                hfrag[kt][ht][i] =
                    (__bf16)Hg[(kt * 32 + hrow + i) * GSZ + ht * 16 + hcol];

    // B operand = x^T tile: lane holds x[tok=lane&15][k=(lane>>4)*8+i]
    const int tokl  = lane & 15;
    const int acolk = (lane >> 4) * 8;
    const int hq    = (lane >> 4) * 4;   // C/D: col=token, row=4 consecutive h
    // store phase: lane -> (row = lane>>4 (+4i), float4 col = lane&15)
    const int srow  = lane >> 4;
    const int sq    = lane & 15;

    const int tok0 = tb * TOK_PER_BLK + wave * (16 * TILES);
    const float* __restrict__ xb =
        x + (size_t)(tok0 + tokl) * DIM + g * GSZ + acolk;
    float* __restrict__ yb =
        y + (size_t)(tok0 + srow) * DIM + g * GSZ + sq * 4;

    // raw[parity][4]: one tile = 4 f32x4
    f32x4 raw[2][4];
    #pragma unroll
    for (int kt = 0; kt < 2; ++kt) {
        raw[0][kt * 2 + 0] = *(const f32x4*)(xb + kt * 32);
        raw[0][kt * 2 + 1] = *(const f32x4*)(xb + kt * 32 + 4);
    }

    #pragma unroll
    for (int tt = 0; tt < TILES; ++tt) {
        // ---- issue next tile's loads first (stay in flight across barriers) ----
        if (tt + 1 < TILES) {
            const float* __restrict__ xp = xb + (size_t)(tt + 1) * 16 * DIM;
            #pragma unroll
            for (int kt = 0; kt < 2; ++kt) {
                raw[(tt + 1) & 1][kt * 2 + 0] = *(const f32x4*)(xp + kt * 32);
                raw[(tt + 1) & 1][kt * 2 + 1] = *(const f32x4*)(xp + kt * 32 + 4);
            }
        }

        // ---- convert current tile to bf16 fragments ----
        bf16x8 xfrag[2];
        #pragma unroll
        for (int kt = 0; kt < 2; ++kt)
            #pragma unroll
            for (int i = 0; i < 4; ++i) {
                xfrag[kt][i]     = (__bf16)raw[tt & 1][kt * 2 + 0][i];
                xfrag[kt][i + 4] = (__bf16)raw[tt & 1][kt * 2 + 1][i];
            }

        // ---- 8 MFMAs: D[h][tok] = sum_k H^T[h][k] x^T[k][tok] ----
        f32x4 acc[4];
        #pragma unroll
        for (int ht = 0; ht < 4; ++ht) {
            acc[ht] = (f32x4){0.f, 0.f, 0.f, 0.f};
            acc[ht] = __builtin_amdgcn_mfma_f32_16x16x32_bf16(
                          hfrag[0][ht], xfrag[0], acc[ht], 0, 0, 0);
            acc[ht] = __builtin_amdgcn_mfma_f32_16x16x32_bf16(
                          hfrag[1][ht], xfrag[1], acc[ht], 0, 0, 0);
        }

        // ---- WAR fence: previous tile's LDS reads done before overwrite ----
        __syncthreads();

        // ---- transpose via per-wave LDS region: T[token][h] ----
        #pragma unroll
        for (int ht = 0; ht < 4; ++ht)
            *(f32x4*)&Tl[wave][tokl][ht * 16 + hq] = acc[ht];

        // ---- RAW fence: cross-lane writes visible before reads ----
        __syncthreads();

        // ---- read back row-major + NT store: 16 lanes x 16B = 256B/row ----
        #pragma unroll
        for (int i = 0; i < 4; ++i) {
            f32x4 v = *(const f32x4*)&Tl[wave][srow + 4 * i][sq * 4];
            __builtin_nontemporal_store(
                v, (f32x4*)(yb + ((size_t)tt * 16 + 4 * i) * DIM));
        }
    }
}

extern "C" void kernel_launch(void* const* d_in, const int* in_sizes, int n_in,
                              void* d_out, int out_size, void* d_ws, size_t ws_size,
                              hipStream_t stream) {
    const float* x = (const float*)d_in[0];
    const float* H = (const float*)d_in[1];
    float* y = (float*)d_out;

    const int ntok = in_sizes[0] / DIM;             // 16384
    const int nblk = (ntok / TOK_PER_BLK) * NG;     // 32 * 64 = 2048

    hipLaunchKernelGGL(hh_mfma_kernel, dim3(nblk), dim3(256), 0, stream,
                       x, H, y, ntok);
}

// Round 8
// 107.139 us; speedup vs baseline: 1.2994x; 1.2994x over previous
//
#include <hip/hip_runtime.h>
#include <hip/hip_bf16.h>

// y[n,g,h] = sum_k x[n,g,k] * H[g,k,h]
// x: [ntok, 4096] fp32, H: [64, 64, 64] fp32, y: [ntok, 4096] fp32.
// Memory-bound. R8 = R4 + ENFORCED 2-tile-deep register pipeline:
// 3 raw buffers, loads for tile tt+2 issued then pinned with
// sched_barrier(0) so the compiler cannot sink them to the use site
// (R4's VGPR=40 proved it did exactly that). Counted vmcnt waits come
// from the compiler; no block barriers anywhere. Stores stay scattered
// NT (R7 refuted the contiguity theory; R5 proved NT is worth 28us).

#define DIM 4096
#define NG   64   // groups per token
#define GSZ  64   // group size
#define TOK_PER_BLK 512
#define TILES 8   // 16-token tiles per wave

typedef __bf16 bf16x8 __attribute__((ext_vector_type(8)));
typedef float  f32x4  __attribute__((ext_vector_type(4)));

__global__ __launch_bounds__(256, 4)
void hh_mfma_kernel(const float* __restrict__ x, const float* __restrict__ H,
                    float* __restrict__ y, int ntok) {
    const int g    = blockIdx.x & (NG - 1);
    const int tb   = blockIdx.x >> 6;
    const int lane = threadIdx.x & 63;
    const int wave = threadIdx.x >> 6;

    // ---- build H^T fragments (A operand) straight from global (L2-hot) ----
    const int hcol = lane & 15;
    const int hrow = (lane >> 4) * 8;
    const float* __restrict__ Hg = H + (size_t)g * (GSZ * GSZ);
    bf16x8 hfrag[2][4];
    #pragma unroll
    for (int kt = 0; kt < 2; ++kt)
        #pragma unroll
        for (int ht = 0; ht < 4; ++ht)
            #pragma unroll
            for (int i = 0; i < 8; ++i)
                hfrag[kt][ht][i] =
                    (__bf16)Hg[(kt * 32 + hrow + i) * GSZ + ht * 16 + hcol];

    // B operand = x^T tile: lane holds x[tok=lane&15][k=(lane>>4)*8+i]
    const int tokl  = lane & 15;
    const int acolk = (lane >> 4) * 8;
    const int hq    = (lane >> 4) * 4;   // C/D: col=token, row=4 consecutive h

    const int tok0 = tb * TOK_PER_BLK + wave * (16 * TILES);
    const float* __restrict__ xb =
        x + (size_t)(tok0 + tokl) * DIM + g * GSZ + acolk;
    float* __restrict__ yb =
        y + (size_t)(tok0 + tokl) * DIM + g * GSZ + hq;

    // 3 rotating raw buffers: tiles tt (consuming), tt+1, tt+2 (in flight)
    f32x4 raw[3][4];

    // prologue: issue tiles 0 and 1, pin them
    #pragma unroll
    for (int t = 0; t < 2; ++t) {
        const float* __restrict__ xp = xb + (size_t)t * 16 * DIM;
        raw[t][0] = *(const f32x4*)(xp);
        raw[t][1] = *(const f32x4*)(xp + 4);
        raw[t][2] = *(const f32x4*)(xp + 32);
        raw[t][3] = *(const f32x4*)(xp + 36);
    }
    __builtin_amdgcn_sched_barrier(0);

    #pragma unroll
    for (int tt = 0; tt < TILES; ++tt) {
        // ---- issue tile tt+2's loads BEFORE tile tt's wait, then pin ----
        if (tt + 2 < TILES) {
            const float* __restrict__ xp = xb + (size_t)(tt + 2) * 16 * DIM;
            raw[(tt + 2) % 3][0] = *(const f32x4*)(xp);
            raw[(tt + 2) % 3][1] = *(const f32x4*)(xp + 4);
            raw[(tt + 2) % 3][2] = *(const f32x4*)(xp + 32);
            raw[(tt + 2) % 3][3] = *(const f32x4*)(xp + 36);
        }
        __builtin_amdgcn_sched_barrier(0);

        // ---- convert tile tt (compiler inserts counted vmcnt wait:
        //      oldest 4 complete, 8 newer loads stay in flight) ----
        bf16x8 xfrag[2];
        #pragma unroll
        for (int kt = 0; kt < 2; ++kt)
            #pragma unroll
            for (int i = 0; i < 4; ++i) {
                xfrag[kt][i]     = (__bf16)raw[tt % 3][kt * 2 + 0][i];
                xfrag[kt][i + 4] = (__bf16)raw[tt % 3][kt * 2 + 1][i];
            }

        // ---- 8 MFMAs: D[h][tok] = sum_k H^T[h][k] x^T[k][tok] ----
        f32x4 acc[4];
        #pragma unroll
        for (int ht = 0; ht < 4; ++ht) {
            acc[ht] = (f32x4){0.f, 0.f, 0.f, 0.f};
            acc[ht] = __builtin_amdgcn_mfma_f32_16x16x32_bf16(
                          hfrag[0][ht], xfrag[0], acc[ht], 0, 0, 0);
            acc[ht] = __builtin_amdgcn_mfma_f32_16x16x32_bf16(
                          hfrag[1][ht], xfrag[1], acc[ht], 0, 0, 0);
        }

        // ---- scattered NT stores (R4 pattern — best measured) ----
        float* __restrict__ yp = yb + (size_t)tt * 16 * DIM;
        #pragma unroll
        for (int ht = 0; ht < 4; ++ht)
            __builtin_nontemporal_store(acc[ht], (f32x4*)(yp + ht * 16));
    }
}

extern "C" void kernel_launch(void* const* d_in, const int* in_sizes, int n_in,
                              void* d_out, int out_size, void* d_ws, size_t ws_size,
                              hipStream_t stream) {
    const float* x = (const float*)d_in[0];
    const float* H = (const float*)d_in[1];
    float* y = (float*)d_out;

    const int ntok = in_sizes[0] / DIM;             // 16384
    const int nblk = (ntok / TOK_PER_BLK) * NG;     // 32 * 64 = 2048

    hipLaunchKernelGGL(hh_mfma_kernel, dim3(nblk), dim3(256), 0, stream,
                       x, H, y, ntok);
}